// Round 4
// baseline (92.024 us; speedup 1.0000x reference)
//
#include <hip/hip_runtime.h>
#include <hip/hip_bf16.h>
#include <float.h>

#define B 16
#define H 32
#define HKV 8
#define G 4
#define D 128
#define LMAX 2048
#define SCALE 0.08838834764831844f  // 1/sqrt(128)

// One block per (b, split); block covers ALL 8 kv heads so each slot is a
// single contiguous 4KB K row + 4KB V row (256 threads x float4 = 1024 floats).
// Thread t owns kv-head h = t>>5 and d-fragment db = (t&31)*4 throughout.
// part_o : [B][HKV][NSPLIT][G][D] unnormalized p*V (written only if split non-empty)
// part_ml: [B][HKV][NSPLIT][G][2] (m, sum_exp)    (always written)
template <int CHUNK>
__global__ __launch_bounds__(256) void attn_partial(
    const float* __restrict__ q,
    const float* __restrict__ kin,
    const float* __restrict__ vin,
    const float* __restrict__ kc,
    const float* __restrict__ vc,
    const int*  __restrict__ slot_mapping,
    const int*  __restrict__ active_slots,
    const int*  __restrict__ context_lens,
    float* __restrict__ part_o,
    float* __restrict__ part_ml)
{
    constexpr int NSPLIT = LMAX / CHUNK;
    const int tid   = threadIdx.x;
    const int split = blockIdx.x % NSPLIT;
    const int b     = blockIdx.x / NSPLIT;

    const int ctx   = context_lens[b];
    const int start = split * CHUNK;
    int nvalid = ctx - start;
    if (nvalid > CHUNK) nvalid = CHUNK;

    if (nvalid <= 0) {
        // mark all 32 (h,g) rows of this split as empty (l = 0)
        if (tid < HKV * G * 2) {
            const int h = tid >> 3, g = (tid >> 1) & 3, w = tid & 1;
            part_ml[(((size_t)(b * HKV + h) * NSPLIT + split) * G + g) * 2 + w] =
                w ? 0.f : -FLT_MAX;
        }
        return;
    }

    __shared__ float sc[CHUNK][HKV * G];   // [slot][(h<<2)+g] scores, then p
    __shared__ const float* kp[CHUNK];     // resolved 4KB K row base (all heads)
    __shared__ const float* vp[CHUNK];
    __shared__ int sm[16];

    if (tid < 16) sm[tid] = slot_mapping[tid];
    __syncthreads();

    // ---- resolve slot -> full-row pointers (one thread per slot)
    if (tid < CHUNK && tid < nvalid) {
        const int s = active_slots[b * LMAX + start + tid];
        int ov = -1;
#pragma unroll
        for (int j = 0; j < 16; ++j)
            if (sm[j] == s) ov = j;
        kp[tid] = (ov >= 0) ? kin + (size_t)ov * (HKV * D) : kc + (size_t)s * (HKV * D);
        vp[tid] = (ov >= 0) ? vin + (size_t)ov * (HKV * D) : vc + (size_t)s * (HKV * D);
    }

    const int h  = tid >> 5;        // kv head owned by this thread
    const int db = (tid & 31) * 4;  // d-fragment

    // q fragments for the 4 query heads of kv-head h (pre-scaled)
    float4 qv[G];
#pragma unroll
    for (int g = 0; g < G; ++g) {
        float4 t = *(const float4*)(q + ((size_t)(b * H + h * G + g)) * D + db);
        qv[g] = make_float4(t.x * SCALE, t.y * SCALE, t.z * SCALE, t.w * SCALE);
    }
    __syncthreads();

    // ---- K pass: one 4KB coalesced load per slot; width-32 dot reduce
#pragma unroll 4
    for (int i = 0; i < nvalid; ++i) {
        const float4 kv = *(const float4*)(kp[i] + tid * 4);
        float pd0 = kv.x * qv[0].x + kv.y * qv[0].y + kv.z * qv[0].z + kv.w * qv[0].w;
        float pd1 = kv.x * qv[1].x + kv.y * qv[1].y + kv.z * qv[1].z + kv.w * qv[1].w;
        float pd2 = kv.x * qv[2].x + kv.y * qv[2].y + kv.z * qv[2].z + kv.w * qv[2].w;
        float pd3 = kv.x * qv[3].x + kv.y * qv[3].y + kv.z * qv[3].z + kv.w * qv[3].w;
#pragma unroll
        for (int msk = 1; msk < 32; msk <<= 1) {
            pd0 += __shfl_xor(pd0, msk, 32);
            pd1 += __shfl_xor(pd1, msk, 32);
            pd2 += __shfl_xor(pd2, msk, 32);
            pd3 += __shfl_xor(pd3, msk, 32);
        }
        if ((tid & 31) == 0)
            *(float4*)&sc[i][h << 2] = make_float4(pd0, pd1, pd2, pd3);
    }
    __syncthreads();

    // ---- softmax: 32 rows x nvalid; 8 threads per row
    {
        const int r = tid >> 3, off = tid & 7;
        float m = -FLT_MAX;
        for (int i = off; i < nvalid; i += 8) m = fmaxf(m, sc[i][r]);
#pragma unroll
        for (int msk = 1; msk < 8; msk <<= 1) m = fmaxf(m, __shfl_xor(m, msk, 8));
        float sum = 0.f;
        for (int i = off; i < nvalid; i += 8) {
            const float p = __expf(sc[i][r] - m);
            sc[i][r] = p;
            sum += p;
        }
#pragma unroll
        for (int msk = 1; msk < 8; msk <<= 1) sum += __shfl_xor(sum, msk, 8);
        if (off == 0) {
            const int hh = r >> 2, g = r & 3;
            const size_t mlb = (((size_t)(b * HKV + hh) * NSPLIT + split) * G + g) * 2;
            part_ml[mlb + 0] = m;
            part_ml[mlb + 1] = sum;
        }
    }
    __syncthreads();

    // ---- V pass: one 4KB coalesced load per slot; no cross-thread reduce
    float4 a0 = {0,0,0,0}, a1 = {0,0,0,0}, a2 = {0,0,0,0}, a3 = {0,0,0,0};
#pragma unroll 4
    for (int i = 0; i < nvalid; ++i) {
        const float4 vv = *(const float4*)(vp[i] + tid * 4);
        const float4 p4 = *(const float4*)&sc[i][h << 2];  // broadcast read
        a0.x += p4.x * vv.x; a0.y += p4.x * vv.y; a0.z += p4.x * vv.z; a0.w += p4.x * vv.w;
        a1.x += p4.y * vv.x; a1.y += p4.y * vv.y; a1.z += p4.y * vv.z; a1.w += p4.y * vv.w;
        a2.x += p4.z * vv.x; a2.y += p4.z * vv.y; a2.z += p4.z * vv.z; a2.w += p4.z * vv.w;
        a3.x += p4.w * vv.x; a3.y += p4.w * vv.y; a3.z += p4.w * vv.z; a3.w += p4.w * vv.w;
    }
    {
        const size_t ob = ((size_t)(b * HKV + h) * NSPLIT + split) * G;
        *(float4*)(part_o + (ob + 0) * D + db) = a0;
        *(float4*)(part_o + (ob + 1) * D + db) = a1;
        *(float4*)(part_o + (ob + 2) * D + db) = a2;
        *(float4*)(part_o + (ob + 3) * D + db) = a3;
    }
}

// Kernel 2: merge nsplit partials per (b, h, g) with log-sum-exp combine.
__global__ __launch_bounds__(128) void attn_reduce(
    const float* __restrict__ part_o,
    const float* __restrict__ part_ml,
    float* __restrict__ out,
    int nsplit)
{
    const int g = blockIdx.x & 3;
    const int h = (blockIdx.x >> 2) & 7;
    const int b = blockIdx.x >> 5;
    const int d = threadIdx.x;

    __shared__ float mlds[128], llds[128];   // max nsplit = 128
    const size_t base = (size_t)(b * HKV + h) * nsplit;

    for (int s = d; s < nsplit; s += 128) {
        mlds[s] = part_ml[((base + s) * G + g) * 2 + 0];
        llds[s] = part_ml[((base + s) * G + g) * 2 + 1];
    }
    __syncthreads();

    float M = -FLT_MAX;
    for (int s = 0; s < nsplit; ++s)
        if (llds[s] > 0.f) M = fmaxf(M, mlds[s]);

    float L = 0.f, acc = 0.f;
    for (int s = 0; s < nsplit; ++s) {
        const float l = llds[s];
        if (l > 0.f) {                       // uniform branch within block
            const float e = __expf(mlds[s] - M);
            L += l * e;
            acc += e * part_o[((base + s) * G + g) * D + d];
        }
    }
    out[((size_t)(b * H) + h * G + g) * D + d] = acc / (L > 0.f ? L : 1.f);
}

extern "C" void kernel_launch(void* const* d_in, const int* in_sizes, int n_in,
                              void* d_out, int out_size, void* d_ws, size_t ws_size,
                              hipStream_t stream) {
    const float* q  = (const float*)d_in[0];
    const float* k  = (const float*)d_in[1];
    const float* v  = (const float*)d_in[2];
    const float* kc = (const float*)d_in[3];
    const float* vc = (const float*)d_in[4];
    const int* slot_mapping = (const int*)d_in[5];
    const int* active_slots = (const int*)d_in[6];
    const int* context_lens = (const int*)d_in[7];
    float* out = (float*)d_out;

    const size_t perSplit = (size_t)B * HKV * (G * D + G * 2) * sizeof(float);
    int nsplit = 16;
    if (ws_size >= 128 * perSplit)      nsplit = 128;
    else if (ws_size >= 64 * perSplit)  nsplit = 64;
    else if (ws_size >= 32 * perSplit)  nsplit = 32;

    float* part_o  = (float*)d_ws;
    float* part_ml = part_o + (size_t)B * HKV * nsplit * G * D;

    if (nsplit == 128) {
        attn_partial<16><<<B * 128, 256, 0, stream>>>(
            q, k, v, kc, vc, slot_mapping, active_slots, context_lens, part_o, part_ml);
    } else if (nsplit == 64) {
        attn_partial<32><<<B * 64, 256, 0, stream>>>(
            q, k, v, kc, vc, slot_mapping, active_slots, context_lens, part_o, part_ml);
    } else if (nsplit == 32) {
        attn_partial<64><<<B * 32, 256, 0, stream>>>(
            q, k, v, kc, vc, slot_mapping, active_slots, context_lens, part_o, part_ml);
    } else {
        attn_partial<128><<<B * 16, 256, 0, stream>>>(
            q, k, v, kc, vc, slot_mapping, active_slots, context_lens, part_o, part_ml);
    }
    attn_reduce<<<B * HKV * G, 128, 0, stream>>>(part_o, part_ml, out, nsplit);
}

// Round 5
// 43.006 us; speedup vs baseline: 2.1398x; 2.1398x over previous
//
#include <hip/hip_runtime.h>
#include <hip/hip_bf16.h>
#include <float.h>

#define B 16
#define H 32
#define HKV 8
#define G 4
#define D 128
#define LMAX 2048
#define BATCH 32
#define SCALE 0.08838834764831844f  // 1/sqrt(128)

// Async global->LDS, 16B per lane. lds_base must be wave-uniform; HW adds lane*16.
__device__ __forceinline__ void stage16(const float* gsrc, float* lds_base, int lane) {
#if __has_builtin(__builtin_amdgcn_global_load_lds)
    __builtin_amdgcn_global_load_lds(
        (const __attribute__((address_space(1))) void*)gsrc,
        (__attribute__((address_space(3))) void*)lds_base, 16, 0, 0);
#else
    *(float4*)((char*)lds_base + lane * 16) = *(const float4*)gsrc;
#endif
}

// Kernel 1: per (b, kv-head, split) flash-decode partial with LDS-staged K/V.
// part_o : [B][HKV][NSPLIT][G][D] unnormalized p*V (written only if split non-empty)
// part_ml: [B][HKV][NSPLIT][G][2] (m, sum_exp)    (always written)
template <int CHUNK>
__global__ __launch_bounds__(256) void attn_partial(
    const float* __restrict__ q,
    const float* __restrict__ kin,
    const float* __restrict__ vin,
    const float* __restrict__ kc,
    const float* __restrict__ vc,
    const int*  __restrict__ slot_mapping,
    const int*  __restrict__ active_slots,
    const int*  __restrict__ context_lens,
    float* __restrict__ part_o,
    float* __restrict__ part_ml)
{
    constexpr int NSPLIT = LMAX / CHUNK;
    const int tid   = threadIdx.x;
    const int split = blockIdx.x % NSPLIT;
    const int h     = (blockIdx.x / NSPLIT) % HKV;
    const int b     = blockIdx.x / (NSPLIT * HKV);

    const int ctx   = context_lens[b];
    const int start = split * CHUNK;
    int nvalid = ctx - start;
    if (nvalid > CHUNK) nvalid = CHUNK;

    const size_t pbase = ((size_t)(b * HKV + h) * NSPLIT + split) * G;

    if (nvalid <= 0) {
        if (tid < G * 2) part_ml[pbase * 2 + tid] = (tid & 1) ? 0.f : -FLT_MAX;
        return;
    }

    __shared__ float stg[2][BATCH * D];     // 2 x 16KB staged K/V rows
    __shared__ float sc[CHUNK][G];          // scores, then p
    __shared__ const float* kp[CHUNK];
    __shared__ const float* vp[CHUNK];
    __shared__ int sm[16];

    if (tid < 16) sm[tid] = slot_mapping[tid];
    __syncthreads();

    // resolve slot -> row pointers (coalesced)
    for (int li = tid; li < nvalid; li += 256) {
        const int s = active_slots[b * LMAX + start + li];
        int ov = -1;
#pragma unroll
        for (int j = 0; j < 16; ++j)
            if (sm[j] == s) ov = j;
        kp[li] = (ov >= 0) ? kin + ((size_t)ov * HKV + h) * D : kc + ((size_t)s * HKV + h) * D;
        vp[li] = (ov >= 0) ? vin + ((size_t)ov * HKV + h) * D : vc + ((size_t)s * HKV + h) * D;
    }

    const int grp   = tid >> 3;   // 0..31 : row within batch (QK)
    const int lane8 = tid & 7;
    const int wv    = tid >> 6;   // wave 0..3
    const int lane  = tid & 63;

    // q fragments (pre-scaled): lane8 owns d = j*32 + lane8*4
    float4 qv[G][4];
#pragma unroll
    for (int g = 0; g < G; ++g) {
        const float* qp = q + ((size_t)(b * H + h * G + g)) * D;
#pragma unroll
        for (int i = 0; i < 4; ++i) {
            float4 t = *(const float4*)(qp + i * 32 + lane8 * 4);
            qv[g][i] = make_float4(t.x * SCALE, t.y * SCALE, t.z * SCALE, t.w * SCALE);
        }
    }
    __syncthreads();   // kp/vp visible before staging

    const int nb = (nvalid + BATCH - 1) / BATCH;

    // stage batch t of ptrs[] into stg[buf]: each wave stages 8 rows = 4 pair-instrs
    auto STAGE = [&](const float* const* ptrs, int t, int buf) {
#pragma unroll
        for (int p = 0; p < 4; ++p) {
            const int r  = wv * 8 + 2 * p + (lane >> 5);   // row in batch
            const int li = t * BATCH + r;
            if (li < nvalid)
                stage16(ptrs[li] + (lane & 31) * 4, &stg[buf][(wv * 8 + 2 * p) * D], lane);
        }
    };

    auto COMPUTE_QK = [&](int t, int buf) {
        const int li = t * BATCH + grp;
        if (li < nvalid) {
            const float* kr = &stg[buf][grp * D];
            float pd0 = 0.f, pd1 = 0.f, pd2 = 0.f, pd3 = 0.f;
#pragma unroll
            for (int j = 0; j < 4; ++j) {
                const float4 kv = *(const float4*)(kr + j * 32 + lane8 * 4);
                pd0 += kv.x * qv[0][j].x + kv.y * qv[0][j].y + kv.z * qv[0][j].z + kv.w * qv[0][j].w;
                pd1 += kv.x * qv[1][j].x + kv.y * qv[1][j].y + kv.z * qv[1][j].z + kv.w * qv[1][j].w;
                pd2 += kv.x * qv[2][j].x + kv.y * qv[2][j].y + kv.z * qv[2][j].z + kv.w * qv[2][j].w;
                pd3 += kv.x * qv[3][j].x + kv.y * qv[3][j].y + kv.z * qv[3][j].z + kv.w * qv[3][j].w;
            }
#pragma unroll
            for (int msk = 1; msk < 8; msk <<= 1) {
                pd0 += __shfl_xor(pd0, msk, 8);
                pd1 += __shfl_xor(pd1, msk, 8);
                pd2 += __shfl_xor(pd2, msk, 8);
                pd3 += __shfl_xor(pd3, msk, 8);
            }
            if (lane8 == 0)
                *(float4*)&sc[li][0] = make_float4(pd0, pd1, pd2, pd3);
        }
    };

    // ---- K pass (double-buffered; V batch 0 prefetched in last iteration)
    STAGE(kp, 0, 0);
    __syncthreads();
    for (int t = 0; t < nb; ++t) {
        if (t + 1 < nb) STAGE(kp, t + 1, (t + 1) & 1);
        else            STAGE(vp, 0, nb & 1);
        COMPUTE_QK(t, t & 1);
        __syncthreads();
    }

    // ---- softmax: wave g handles head g (V0 fetch in flight underneath)
    {
        const int g = wv;
        float m = -FLT_MAX;
        for (int i = lane; i < nvalid; i += 64) m = fmaxf(m, sc[i][g]);
#pragma unroll
        for (int msk = 1; msk < 64; msk <<= 1) m = fmaxf(m, __shfl_xor(m, msk, 64));
        float sum = 0.f;
        for (int i = lane; i < nvalid; i += 64) {
            const float p = __expf(sc[i][g] - m);
            sc[i][g] = p;
            sum += p;
        }
#pragma unroll
        for (int msk = 1; msk < 64; msk <<= 1) sum += __shfl_xor(sum, msk, 64);
        if (lane == 0) {
            part_ml[(pbase + g) * 2 + 0] = m;
            part_ml[(pbase + g) * 2 + 1] = sum;
        }
    }
    __syncthreads();

    // ---- V pass: grp8 owns rows r === grp8 (mod 8); dl owns d-frag; all 4 heads
    const int grp8 = tid >> 5;
    const int dl   = tid & 31;
    float4 a0 = {0,0,0,0}, a1 = {0,0,0,0}, a2 = {0,0,0,0}, a3 = {0,0,0,0};
    for (int t = 0; t < nb; ++t) {
        if (t + 1 < nb) STAGE(vp, t + 1, (nb + t + 1) & 1);
        const int buf = (nb + t) & 1;
#pragma unroll
        for (int ii = 0; ii < 4; ++ii) {
            const int r  = ii * 8 + grp8;
            const int li = t * BATCH + r;
            if (li < nvalid) {
                const float4 vv = *(const float4*)(&stg[buf][r * D + dl * 4]);
                const float4 p4 = *(const float4*)&sc[li][0];
                a0.x += p4.x * vv.x; a0.y += p4.x * vv.y; a0.z += p4.x * vv.z; a0.w += p4.x * vv.w;
                a1.x += p4.y * vv.x; a1.y += p4.y * vv.y; a1.z += p4.y * vv.z; a1.w += p4.y * vv.w;
                a2.x += p4.z * vv.x; a2.y += p4.z * vv.y; a2.z += p4.z * vv.z; a2.w += p4.z * vv.w;
                a3.x += p4.w * vv.x; a3.y += p4.w * vv.y; a3.z += p4.w * vv.z; a3.w += p4.w * vv.w;
            }
        }
        __syncthreads();
    }

    // ---- cross-group combine: alias red[8][G][D] onto stg[0] (dead now)
    {
        float* red = &stg[0][0];   // 8*4*128 floats = 16KB
        *(float4*)&red[((grp8 * G + 0) * D) + dl * 4] = a0;
        *(float4*)&red[((grp8 * G + 1) * D) + dl * 4] = a1;
        *(float4*)&red[((grp8 * G + 2) * D) + dl * 4] = a2;
        *(float4*)&red[((grp8 * G + 3) * D) + dl * 4] = a3;
        __syncthreads();
#pragma unroll
        for (int k2 = 0; k2 < 2; ++k2) {
            const int o = tid * 2 + k2;     // [G][D] flat
            const int g = o >> 7, d = o & 127;
            float s = 0.f;
#pragma unroll
            for (int r = 0; r < 8; ++r) s += red[(r * G + g) * D + d];
            part_o[(pbase + g) * D + d] = s;
        }
    }
}

// Kernel 2: merge nsplit partials per (b, h, g) with log-sum-exp combine.
__global__ __launch_bounds__(128) void attn_reduce(
    const float* __restrict__ part_o,
    const float* __restrict__ part_ml,
    float* __restrict__ out,
    int nsplit)
{
    const int g = blockIdx.x & 3;
    const int h = (blockIdx.x >> 2) & 7;
    const int b = blockIdx.x >> 5;
    const int d = threadIdx.x;

    __shared__ float mlds[32], llds[32];
    const size_t base = (size_t)(b * HKV + h) * nsplit;

    for (int s = d; s < nsplit; s += 128) {
        mlds[s] = part_ml[((base + s) * G + g) * 2 + 0];
        llds[s] = part_ml[((base + s) * G + g) * 2 + 1];
    }
    __syncthreads();

    float M = -FLT_MAX;
    for (int s = 0; s < nsplit; ++s)
        if (llds[s] > 0.f) M = fmaxf(M, mlds[s]);

    float L = 0.f, acc = 0.f;
    for (int s = 0; s < nsplit; ++s) {
        const float l = llds[s];
        if (l > 0.f) {
            const float e = __expf(mlds[s] - M);
            L += l * e;
            acc += e * part_o[((base + s) * G + g) * D + d];
        }
    }
    out[((size_t)(b * H) + h * G + g) * D + d] = acc / (L > 0.f ? L : 1.f);
}

extern "C" void kernel_launch(void* const* d_in, const int* in_sizes, int n_in,
                              void* d_out, int out_size, void* d_ws, size_t ws_size,
                              hipStream_t stream) {
    const float* q  = (const float*)d_in[0];
    const float* k  = (const float*)d_in[1];
    const float* v  = (const float*)d_in[2];
    const float* kc = (const float*)d_in[3];
    const float* vc = (const float*)d_in[4];
    const int* slot_mapping = (const int*)d_in[5];
    const int* active_slots = (const int*)d_in[6];
    const int* context_lens = (const int*)d_in[7];
    float* out = (float*)d_out;

    const size_t perSplit = (size_t)B * HKV * (G * D + G * 2) * sizeof(float);
    const int nsplit = (ws_size >= 16 * perSplit) ? 16 : 8;

    float* part_o  = (float*)d_ws;
    float* part_ml = part_o + (size_t)B * HKV * nsplit * G * D;

    if (nsplit == 16) {
        attn_partial<128><<<B * HKV * 16, 256, 0, stream>>>(
            q, k, v, kc, vc, slot_mapping, active_slots, context_lens, part_o, part_ml);
    } else {
        attn_partial<256><<<B * HKV * 8, 256, 0, stream>>>(
            q, k, v, kc, vc, slot_mapping, active_slots, context_lens, part_o, part_ml);
    }
    attn_reduce<<<B * HKV * G, 128, 0, stream>>>(part_o, part_ml, out, nsplit);
}